// Round 9
// baseline (1322.502 us; speedup 1.0000x reference)
//
#include <hip/hip_runtime.h>

typedef unsigned short u16;
typedef unsigned int   u32;
typedef unsigned long long u64;
typedef short s8v __attribute__((ext_vector_type(8)));   // 8 bf16 (4 VGPRs)
typedef float f4v __attribute__((ext_vector_type(4)));   // 4 fp32 acc
typedef float f2v __attribute__((ext_vector_type(2)));   // packed fp32 pair

#define STRIDE 168           // LDS A-row stride in elems (336B, 16B-aligned rows)
#define CAP 256              // ball-query cap (Poisson lambda~137, P(>256)~1e-24)
#define OFF_G1 0             // swizzled-weight elem offsets in ws (128 KiB total)
#define OFF_G2 12288
#define OFF_G3 28672
#define OFF_G4 49152

__device__ __forceinline__ float bf2f(u16 u){ return __uint_as_float(((u32)u)<<16); }
__device__ __forceinline__ u16 f2bf(float f){
  u32 u = __float_as_uint(f);
  return (u16)((u + 0x7FFFu + ((u>>16)&1u)) >> 16);      // RNE
}
// exact fp32, no-FMA, numpy order: (dx*dx + dy*dy) + dz*dz
__device__ __forceinline__ float sqd(float ax,float ay,float az,float bx,float by,float bz){
  float dx=ax-bx, dy=ay-by, dz=az-bz;
  return __fadd_rn(__fadd_rn(__fmul_rn(dx,dx),__fmul_rn(dy,dy)),__fmul_rn(dz,dz));
}

// DPP u32 max step (dist bits are positive floats -> unsigned == float ordering)
#define WMAX_STEP(v, CTRL) { \
  u32 _t = (u32)__builtin_amdgcn_update_dpp(0, (int)(v), CTRL, 0xf, 0xf, false); \
  (v) = (v) > _t ? (v) : _t; }

// ---------------------------------------------------------------- FPS
// one block per batch; 4 waves, 16 contiguous pts/thread. Leader pushes
// (key,x,y,z) pre-barrier; post-barrier merge is 4 broadcast reads + 3 selects.
__global__ __launch_bounds__(256) void fps_kernel(const float* __restrict__ xyz,
                                                  float* __restrict__ newxyz){
  __shared__ __align__(16) float S[4096*3];
  __shared__ __align__(32) float red[2][4][8];   // key_lo,key_hi,x,y,z,pad[3]
  const int b = blockIdx.x, tid = threadIdx.x;
  const int lane = tid & 63, wv = tid >> 6;
  const float* xb = xyz + (size_t)b*4096*3;
  #pragma unroll
  for(int j=0;j<12;j++) ((float4*)S)[j*256+tid] = ((const float4*)xb)[j*256+tid];
  __syncthreads();
  f2v X[8],Y[8],Z[8],DM[8];
  const float x0=S[0], y0=S[1], z0=S[2];
  {
    #pragma clang fp contract(off)
    const f2v fx2={x0,x0}, fy2={y0,y0}, fz2={z0,z0};
    #pragma unroll
    for(int k2=0;k2<8;k2++){
      int p0 = tid*16 + 2*k2;
      X[k2] = (f2v){S[p0*3],   S[p0*3+3]};
      Y[k2] = (f2v){S[p0*3+1], S[p0*3+4]};
      Z[k2] = (f2v){S[p0*3+2], S[p0*3+5]};
      f2v dx=X[k2]-fx2, dy=Y[k2]-fy2, dz=Z[k2]-fz2;
      DM[k2] = (dx*dx + dy*dy) + dz*dz;
    }
  }
  if(tid==0){
    size_t o=(size_t)b*1024*3;
    newxyz[o]=x0; newxyz[o+1]=y0; newxyz[o+2]=z0;
  }
  for(int i=1;i<1024;i++){
    // local argmax over 16 pts (strict > keeps first occurrence)
    float vm = DM[0][0]; int jm = 0;
    #pragma unroll
    for(int j=1;j<16;j++){
      float dj = DM[j>>1][j&1];
      bool g = dj > vm; vm = g ? dj : vm; jm = g ? j : jm;
    }
    // candidate xyz from registers: 7-select tree on idx=jm>>1, elem jm&1
    int idx = jm>>1;
    f2v xa=(idx&1)?X[1]:X[0], xb2=(idx&1)?X[3]:X[2], xc=(idx&1)?X[5]:X[4], xd=(idx&1)?X[7]:X[6];
    f2v ya=(idx&1)?Y[1]:Y[0], yb2=(idx&1)?Y[3]:Y[2], yc=(idx&1)?Y[5]:Y[4], yd=(idx&1)?Y[7]:Y[6];
    f2v za=(idx&1)?Z[1]:Z[0], zb2=(idx&1)?Z[3]:Z[2], zc=(idx&1)?Z[5]:Z[4], zd=(idx&1)?Z[7]:Z[6];
    f2v xe=(idx&2)?xb2:xa, xf=(idx&2)?xd:xc;
    f2v ye=(idx&2)?yb2:ya, yf=(idx&2)?yd:yc;
    f2v ze=(idx&2)?zb2:za, zf=(idx&2)?zd:zc;
    f2v xg=(idx&4)?xf:xe, yg=(idx&4)?yf:ye, zg=(idx&4)?zf:ze;
    float cxx=(jm&1)?xg[1]:xg[0], cyy=(jm&1)?yg[1]:yg[0], czz=(jm&1)?zg[1]:zg[0];
    // wave max via DPP (6 VALU steps), result in lane 63
    u32 w = __float_as_uint(vm);
    WMAX_STEP(w, 0x111); WMAX_STEP(w, 0x112); WMAX_STEP(w, 0x114);
    WMAX_STEP(w, 0x118); WMAX_STEP(w, 0x142); WMAX_STEP(w, 0x143);
    u32 wm = (u32)__builtin_amdgcn_readlane((int)w, 63);
    u64 msk = __ballot(__float_as_uint(vm) == wm);
    int ldr = __ffsll((unsigned long long)msk) - 1;
    if(lane==ldr){
      int p = (wv*64 + lane)*16 + jm;
      float* rr = red[i&1][wv];
      rr[0]=__uint_as_float(~(u32)p); rr[1]=__uint_as_float(wm);
      rr[2]=cxx; rr[3]=cyy; rr[4]=czz;
    }
    __syncthreads();
    // merge 4 candidates (broadcast reads, register selects)
    const float* r0=red[i&1][0]; const float* r1=red[i&1][1];
    const float* r2=red[i&1][2]; const float* r3=red[i&1][3];
    float4 q0=*(const float4*)r0, q1=*(const float4*)r1,
           q2=*(const float4*)r2, q3=*(const float4*)r3;
    float z0v=r0[4], z1v=r1[4], z2v=r2[4], z3v=r3[4];
    u64 k0=((u64)__float_as_uint(q0.y)<<32)|__float_as_uint(q0.x);
    u64 k1=((u64)__float_as_uint(q1.y)<<32)|__float_as_uint(q1.x);
    u64 k2=((u64)__float_as_uint(q2.y)<<32)|__float_as_uint(q2.x);
    u64 k3=((u64)__float_as_uint(q3.y)<<32)|__float_as_uint(q3.x);
    bool g1 = k1>k0; u64 ka=g1?k1:k0;
    float ax=g1?q1.z:q0.z, ay=g1?q1.w:q0.w, az=g1?z1v:z0v;
    bool g2 = k3>k2; u64 kb=g2?k3:k2;
    float bx=g2?q3.z:q2.z, by=g2?q3.w:q2.w, bz=g2?z3v:z2v;
    bool g3 = kb>ka;
    float fx=g3?bx:ax, fy=g3?by:ay, fz=g3?bz:az;
    if(tid==0){
      size_t o=((size_t)b*1024+i)*3;
      newxyz[o]=fx; newxyz[o+1]=fy; newxyz[o+2]=fz;
    }
    {
      #pragma clang fp contract(off)
      const f2v fx2={fx,fx}, fy2={fy,fy}, fz2={fz,fz};
      #pragma unroll
      for(int k2c=0;k2c<8;k2c++){
        f2v dx=X[k2c]-fx2, dy=Y[k2c]-fy2, dz=Z[k2c]-fz2;
        f2v s = (dx*dx + dy*dy) + dz*dz;
        DM[k2c] = __builtin_elementwise_min(DM[k2c], s);
      }
    }
  }
}

// ---------------------------------------------------------------- weight swizzle (f32 -> bf16 frags)
// B-frag-major: frag(c,t,lane) elem j = W[k'][t*16+(lane&15)], k'=c*32+(lane>>4)*8+j;
// G1/G3 row remap: 0..2 -> xyz rows, 3..31 -> zero, 32.. -> rows 3..
__global__ __launch_bounds__(256) void swz_kernel(const float* __restrict__ W1,const float* __restrict__ W2,
                                                  const float* __restrict__ W3,const float* __restrict__ W4,
                                                  u16* __restrict__ wsw){
  int T = blockIdx.x*256 + threadIdx.x;       // 8192 threads
  const float* W; int rel, base, kind;
  if(T < 1536){ rel=T;      base=OFF_G1; W=W1; kind=0; }
  else if(T < 3584){ rel=T-1536; base=OFF_G2; W=W2; kind=1; }
  else if(T < 6144){ rel=T-3584; base=OFF_G3; W=W3; kind=0; }
  else         { rel=T-6144; base=OFF_G4; W=W4; kind=1; }
  int chunk=rel>>6, lane=rel&63, c=chunk>>3, t=chunk&7, quad=lane>>4, l15=lane&15;
  u16 v[8];
  #pragma unroll
  for(int j=0;j<8;j++){
    int kp = c*32 + quad*8 + j, n = t*16 + l15;
    int src = (kind==0) ? (kp<3 ? kp : (kp>=32 ? kp-29 : -1)) : kp;
    v[j] = (src<0) ? (u16)0 : f2bf(W[src*128 + n]);
  }
  int4 o;
  o.x=(int)((u32)v[0]|((u32)v[1]<<16)); o.y=(int)((u32)v[2]|((u32)v[3]<<16));
  o.z=(int)((u32)v[4]|((u32)v[5]<<16)); o.w=(int)((u32)v[6]|((u32)v[7]<<16));
  *(int4*)&wsw[base + rel*8] = o;
}

// ---------------------------------------------------------------- fused ballq + MLP
__device__ __forceinline__ void zero_C(f4v C[2][8]){
  #pragma unroll
  for(int mt=0;mt<2;mt++)
    #pragma unroll
    for(int t=0;t<8;t++) C[mt][t] = (f4v){0.f,0.f,0.f,0.f};
}
__device__ __forceinline__ void load_bias(const float* bsrc,int l15,float bb[8]){
  #pragma unroll
  for(int t=0;t<8;t++) bb[t]=bsrc[t*16+l15];
}
template<int KC>
__device__ __forceinline__ void run_gemm(const u16* A, const u16* BW,
                                         int lane,int l15,int quad, f4v C[2][8]){
  s8v af[2][KC];
  #pragma unroll
  for(int mt=0;mt<2;mt++)
    #pragma unroll
    for(int c=0;c<KC;c++)
      af[mt][c] = *(const s8v*)&A[(mt*16+l15)*STRIDE + c*32 + quad*8];
  #pragma unroll
  for(int t=0;t<8;t++){
    #pragma unroll
    for(int c=0;c<KC;c++){
      s8v bw = *(const s8v*)&BW[((c*8+t)*64 + lane)*8];
      C[0][t] = __builtin_amdgcn_mfma_f32_16x16x32_bf16(af[0][c],bw,C[0][t],0,0,0);
      C[1][t] = __builtin_amdgcn_mfma_f32_16x16x32_bf16(af[1][c],bw,C[1][t],0,0,0);
    }
  }
}
__device__ __forceinline__ void store_act(u16* A,int l15,int quad,f4v C[2][8],const float bb[8]){
  #pragma unroll
  for(int mt=0;mt<2;mt++)
    #pragma unroll
    for(int t=0;t<8;t++)
      #pragma unroll
      for(int r=0;r<4;r++){
        float v = fmaxf(C[mt][t][r]+bb[t], 0.f);
        A[(mt*16+quad*4+r)*STRIDE + t*16 + l15] = f2bf(v);
      }
}
__device__ __forceinline__ void write_xyz_chunk0(u16* A,int lane,float xn,float yn,float zn){
  if(lane<32){
    u16* row=&A[lane*STRIDE];
    row[0]=f2bf(xn); row[1]=f2bf(yn); row[2]=f2bf(zn); row[3]=0;
    #pragma unroll
    for(int q=0;q<7;q++) *(u64*)&row[4+q*4] = 0ull;   // cols 4..31 zero
  }
}

__global__ __launch_bounds__(256,3) void mlp_kernel(const float* __restrict__ xyz,
    const float* __restrict__ feats, const u16* __restrict__ wsw,
    const float* __restrict__ b1,const float* __restrict__ b2,const float* __restrict__ b3,const float* __restrict__ b4,
    const float* __restrict__ newxyz, float* __restrict__ fout){
  __shared__ __align__(16) u16 Abuf[4][32*STRIDE];
  __shared__ u64 Bcand[4][CAP];
  __shared__ int selbuf[4][32];
  const int tid=threadIdx.x, wv=tid>>6, lane=tid&63, quad=lane>>4, l15=lane&15;
  const int widx = blockIdx.x*4 + wv, b = widx>>10;
  u16* A = Abuf[wv];
  const float* xb = xyz + (size_t)b*4096*3;
  // exact f32 FPS center
  const float cx=newxyz[widx*3], cy=newxyz[widx*3+1], cz=newxyz[widx*3+2];

  // ---- ball query (per wave; dedicated LDS candidate buffer) ----
  {
    u64* Bc = Bcand[wv];
    int* sel = selbuf[wv];
    const u64 lt = (1ull<<lane)-1ull;
    int base=0;
    for(int kk=0;kk<64;kk++){
      int p = kk*64 + lane;
      float d = sqd(cx,cy,cz, xb[p*3],xb[p*3+1],xb[p*3+2]);
      bool in = (d <= 0.04f);
      u64 m = __ballot(in);
      if(in){ int pos = base + __popcll(m&lt); if(pos<CAP) Bc[pos] = ((u64)__float_as_uint(d)<<32)|(u32)p; }
      base += __popcll(m);
    }
    int cnt = base>CAP ? CAP : base;
    if(cnt > 32){
      for(int c=lane; c<cnt; c+=64){
        u64 key = Bc[c]; int r=0;
        for(int t2=0;t2<cnt;t2++) r += (Bc[t2] < key) ? 1 : 0;
        if(r < 32) sel[r] = (int)(u32)key;   // low 32 = point index
      }
    } else {
      for(int c=lane; c<cnt; c+=64) sel[c] = (int)(u32)Bc[c];
      int need = 32 - cnt, b2 = 0;
      for(int kk=0; kk<64 && b2<need; kk++){
        int p = kk*64 + lane;
        float d = sqd(cx,cy,cz, xb[p*3],xb[p*3+1],xb[p*3+2]);
        bool o = !(d <= 0.04f);
        u64 m = __ballot(o);
        if(o){ int pos = b2 + __popcll(m&lt); if(pos<need) sel[cnt+pos] = p; }
        b2 += __popcll(m);
      }
    }
  }
  const int* sel = selbuf[wv];             // same wave wrote it
  const int gi_f = sel[lane>>1] & 4095;
  const int gi_x = sel[lane & 31] & 4095;

  // ---- stage grouped features (f32 -> bf16) -> cols 32..95 ----
  {
    int r2=lane>>1, h=lane&1;
    const float* fs = feats + ((size_t)b*4096 + gi_f)*64 + h*32;
    u16* fd = &A[r2*STRIDE + 32 + h*32];
    #pragma unroll
    for(int j=0;j<8;j++){
      float4 v4 = ((const float4*)fs)[j];
      u64 pk4 = (u64)f2bf(v4.x) | ((u64)f2bf(v4.y)<<16)
              | ((u64)f2bf(v4.z)<<32) | ((u64)f2bf(v4.w)<<48);
      *(u64*)&fd[j*4] = pk4;
    }
  }
  // ---- grouped_xyz_norm -> chunk0 cols 0..2 (+ zero pad 3..31) ----
  float xn=0.f,yn=0.f,zn=0.f;
  if(lane<32){
    const float* xp = xb + (size_t)gi_x*3;
    xn = xp[0]-cx; yn = xp[1]-cy; zn = xp[2]-cz;
  }
  write_xyz_chunk0(A,lane,xn,yn,zn);
  __syncthreads();

  f4v C[2][8]; float bb[8];
  // GEMM1: f_in(32x96) @ W1 -> relu -> H1
  zero_C(C); load_bias(b1,l15,bb);
  run_gemm<3>(A, wsw+OFF_G1, lane,l15,quad, C);
  store_act(A,l15,quad,C,bb);
  __syncthreads();
  // GEMM2: H1 @ W2 -> relu -> f_prime
  zero_C(C); load_bias(b2,l15,bb);
  run_gemm<4>(A, wsw+OFF_G2, lane,l15,quad, C);
  float fp[2][8][4]; float mean[8];
  #pragma unroll
  for(int t=0;t<8;t++){
    float s=0.f;
    #pragma unroll
    for(int mt=0;mt<2;mt++)
      #pragma unroll
      for(int r=0;r<4;r++){
        float v = fmaxf(C[mt][t][r]+bb[t], 0.f);
        fp[mt][t][r]=v; s+=v;
      }
    s += __shfl_xor(s,16); s += __shfl_xor(s,32);
    mean[t] = s*0.03125f;
  }
  #pragma unroll
  for(int mt=0;mt<2;mt++)
    #pragma unroll
    for(int t=0;t<8;t++)
      #pragma unroll
      for(int r=0;r<4;r++)
        A[(mt*16+quad*4+r)*STRIDE + 32 + t*16 + l15] = f2bf(fp[mt][t][r]-mean[t]);
  write_xyz_chunk0(A,lane,xn,yn,zn);   // w_in chunk0
  __syncthreads();
  // GEMM3: w_in(32x160) @ W3 -> relu -> H3
  zero_C(C); load_bias(b3,l15,bb);
  run_gemm<5>(A, wsw+OFF_G3, lane,l15,quad, C);
  store_act(A,l15,quad,C,bb);
  __syncthreads();
  // GEMM4: H3 @ W4 -> sigmoid -> alpha; f_out = sum_k alpha*f_prime
  zero_C(C); load_bias(b4,l15,bb);
  run_gemm<4>(A, wsw+OFF_G4, lane,l15,quad, C);
  float* fo = fout + (size_t)widx*128;
  #pragma unroll
  for(int t=0;t<8;t++){
    float part=0.f;
    #pragma unroll
    for(int mt=0;mt<2;mt++)
      #pragma unroll
      for(int r=0;r<4;r++){
        float pre = C[mt][t][r]+bb[t];
        float a = 1.f/(1.f+__expf(-pre));
        part += a*fp[mt][t][r];
      }
    part += __shfl_xor(part,16); part += __shfl_xor(part,32);
    if(quad==0) fo[t*16+l15] = part;
  }
}

// ---------------------------------------------------------------- launch
extern "C" void kernel_launch(void* const* d_in, const int* in_sizes, int n_in,
                              void* d_out, int out_size, void* d_ws, size_t ws_size,
                              hipStream_t stream){
  (void)in_sizes; (void)n_in; (void)out_size; (void)ws_size;
  const float* xyz   = (const float*)d_in[0];
  const float* feats = (const float*)d_in[1];
  const float* W1 = (const float*)d_in[2]; const float* b1 = (const float*)d_in[3];
  const float* W2 = (const float*)d_in[4]; const float* b2 = (const float*)d_in[5];
  const float* W3 = (const float*)d_in[6]; const float* b3 = (const float*)d_in[7];
  const float* W4 = (const float*)d_in[8]; const float* b4 = (const float*)d_in[9];
  float* out = (float*)d_out;
  float* newxyz = out;               // (16,1024,3) f32
  float* fout   = out + 16*1024*3;   // (16,1024,128) f32
  u16* wsw = (u16*)d_ws;             // 128 KiB swizzled bf16 weights — only ws use

  hipLaunchKernelGGL(swz_kernel, dim3(32),   dim3(256), 0, stream, W1,W2,W3,W4, wsw);
  hipLaunchKernelGGL(fps_kernel, dim3(16),   dim3(256), 0, stream, xyz, newxyz);
  hipLaunchKernelGGL(mlp_kernel, dim3(4096), dim3(256), 0, stream,
                     xyz, feats, wsw, b1,b2,b3,b4, newxyz, fout);
}

// Round 10
// 1010.237 us; speedup vs baseline: 1.3091x; 1.3091x over previous
//
#include <hip/hip_runtime.h>

typedef unsigned short u16;
typedef unsigned int   u32;
typedef unsigned long long u64;
typedef short s8v __attribute__((ext_vector_type(8)));   // 8 bf16 (4 VGPRs)
typedef float f4v __attribute__((ext_vector_type(4)));   // 4 fp32 acc
typedef float f2v __attribute__((ext_vector_type(2)));   // packed fp32 pair

#define STRIDE 168           // LDS A-row stride in elems (336B, 16B-aligned rows)
#define CAP 256              // ball-query cap (Poisson lambda~137, P(>256)~1e-24)
#define OFF_G1 0             // swizzled-weight elem offsets in ws (128 KiB total)
#define OFF_G2 12288
#define OFF_G3 28672
#define OFF_G4 49152

__device__ __forceinline__ float bf2f(u16 u){ return __uint_as_float(((u32)u)<<16); }
__device__ __forceinline__ u16 f2bf(float f){
  u32 u = __float_as_uint(f);
  return (u16)((u + 0x7FFFu + ((u>>16)&1u)) >> 16);      // RNE
}
// exact fp32, no-FMA, numpy order: (dx*dx + dy*dy) + dz*dz
__device__ __forceinline__ float sqd(float ax,float ay,float az,float bx,float by,float bz){
  float dx=ax-bx, dy=ay-by, dz=az-bz;
  return __fadd_rn(__fadd_rn(__fmul_rn(dx,dx),__fmul_rn(dy,dy)),__fmul_rn(dz,dz));
}

// DPP u32 max step (dist bits are positive floats -> unsigned == float ordering)
#define WMAX_STEP(v, CTRL) { \
  u32 _t = (u32)__builtin_amdgcn_update_dpp(0, (int)(v), CTRL, 0xf, 0xf, false); \
  (v) = (v) > _t ? (v) : _t; }
// u64 max step via quad_perm (all lanes valid)
#define QMAX64(k, CTRL) { \
  u32 _lo=(u32)(k), _hi=(u32)((k)>>32); \
  u32 _plo=(u32)__builtin_amdgcn_update_dpp(0,(int)_lo,CTRL,0xf,0xf,true); \
  u32 _phi=(u32)__builtin_amdgcn_update_dpp(0,(int)_hi,CTRL,0xf,0xf,true); \
  u64 _o=((u64)_phi<<32)|_plo; (k) = (k)>_o ? (k) : _o; }

// ---------------------------------------------------------------- FPS
// one block per batch; 4 waves, 16 contiguous pts/thread. R8 merge structure;
// results buffered in LDS (no global store inside the barrier loop);
// tree-argmax (pk-max value tree + equality mask + ffs).
__global__ __launch_bounds__(256) void fps_kernel(const float* __restrict__ xyz,
                                                  float* __restrict__ newxyz){
  __shared__ __align__(16) float S[4096*3];   // 48 KB points
  __shared__ __align__(16) float R[1024*3];   // 12 KB results
  __shared__ u64 red[2][4];
  const int b = blockIdx.x, tid = threadIdx.x;
  const int lane = tid & 63, wv = tid >> 6;
  const float* xb = xyz + (size_t)b*4096*3;
  #pragma unroll
  for(int j=0;j<12;j++) ((float4*)S)[j*256+tid] = ((const float4*)xb)[j*256+tid];
  __syncthreads();
  f2v X[8],Y[8],Z[8],DM[8];
  const float x0=S[0], y0=S[1], z0=S[2];
  {
    #pragma clang fp contract(off)
    const f2v fx2={x0,x0}, fy2={y0,y0}, fz2={z0,z0};
    #pragma unroll
    for(int k2=0;k2<8;k2++){
      int p0 = tid*16 + 2*k2;
      X[k2] = (f2v){S[p0*3],   S[p0*3+3]};
      Y[k2] = (f2v){S[p0*3+1], S[p0*3+4]};
      Z[k2] = (f2v){S[p0*3+2], S[p0*3+5]};
      f2v dx=X[k2]-fx2, dy=Y[k2]-fy2, dz=Z[k2]-fz2;
      DM[k2] = (dx*dx + dy*dy) + dz*dz;
    }
  }
  if(tid==0){ R[0]=x0; R[1]=y0; R[2]=z0; }
  for(int i=1;i<1024;i++){
    // value max: pk tree (depth 4)
    f2v a = __builtin_elementwise_max(__builtin_elementwise_max(DM[0],DM[1]),
                                      __builtin_elementwise_max(DM[2],DM[3]));
    f2v c = __builtin_elementwise_max(__builtin_elementwise_max(DM[4],DM[5]),
                                      __builtin_elementwise_max(DM[6],DM[7]));
    f2v mm = __builtin_elementwise_max(a,c);
    float vm = fmaxf(mm[0], mm[1]);
    // first-occurrence local index via equality mask + ffs
    u32 m16 = 0;
    #pragma unroll
    for(int j=0;j<16;j++) m16 |= (DM[j>>1][j&1]==vm) ? (1u<<j) : 0u;
    int jm = __ffs(m16)-1;
    // wave max via DPP (6 VALU steps), result in lane 63
    u32 w = __float_as_uint(vm);
    WMAX_STEP(w, 0x111); WMAX_STEP(w, 0x112); WMAX_STEP(w, 0x114);
    WMAX_STEP(w, 0x118); WMAX_STEP(w, 0x142); WMAX_STEP(w, 0x143);
    u32 wm = (u32)__builtin_amdgcn_readlane((int)w, 63);
    u64 msk = __ballot(__float_as_uint(vm) == wm);
    int ldr = __ffsll((unsigned long long)msk) - 1;
    int pj  = __builtin_amdgcn_readlane(jm, ldr);
    int p   = (wv*64 + ldr)*16 + pj;
    if(lane==0) red[i&1][wv] = ((u64)wm<<32) | (u32)(~(u32)p);
    __syncthreads();
    u64 k = red[i&1][lane&3];
    QMAX64(k, 0xB1); QMAX64(k, 0x4E);
    int far = (int)(~(u32)k) & 4095;
    float fx=S[far*3], fy=S[far*3+1], fz=S[far*3+2];
    if(tid==0){ R[i*3]=fx; R[i*3+1]=fy; R[i*3+2]=fz; }   // LDS only — no vmcnt at barrier
    {
      #pragma clang fp contract(off)
      const f2v fx2={fx,fx}, fy2={fy,fy}, fz2={fz,fz};
      #pragma unroll
      for(int k2c=0;k2c<8;k2c++){
        f2v dx=X[k2c]-fx2, dy=Y[k2c]-fy2, dz=Z[k2c]-fz2;
        f2v s = (dx*dx + dy*dy) + dz*dz;
        DM[k2c] = __builtin_elementwise_min(DM[k2c], s);
      }
    }
  }
  __syncthreads();
  // coalesced dump: 1024*3 floats = 768 float4
  float* nb = newxyz + (size_t)b*3072;
  #pragma unroll
  for(int j=0;j<3;j++) ((float4*)nb)[j*256+tid] = ((const float4*)R)[j*256+tid];
}

// ---------------------------------------------------------------- weight swizzle (f32 -> bf16 frags)
// B-frag-major: frag(c,t,lane) elem j = W[k'][t*16+(lane&15)], k'=c*32+(lane>>4)*8+j;
// G1/G3 row remap: 0..2 -> xyz rows, 3..31 -> zero, 32.. -> rows 3..
__global__ __launch_bounds__(256) void swz_kernel(const float* __restrict__ W1,const float* __restrict__ W2,
                                                  const float* __restrict__ W3,const float* __restrict__ W4,
                                                  u16* __restrict__ wsw){
  int T = blockIdx.x*256 + threadIdx.x;       // 8192 threads
  const float* W; int rel, base, kind;
  if(T < 1536){ rel=T;      base=OFF_G1; W=W1; kind=0; }
  else if(T < 3584){ rel=T-1536; base=OFF_G2; W=W2; kind=1; }
  else if(T < 6144){ rel=T-3584; base=OFF_G3; W=W3; kind=0; }
  else         { rel=T-6144; base=OFF_G4; W=W4; kind=1; }
  int chunk=rel>>6, lane=rel&63, c=chunk>>3, t=chunk&7, quad=lane>>4, l15=lane&15;
  u16 v[8];
  #pragma unroll
  for(int j=0;j<8;j++){
    int kp = c*32 + quad*8 + j, n = t*16 + l15;
    int src = (kind==0) ? (kp<3 ? kp : (kp>=32 ? kp-29 : -1)) : kp;
    v[j] = (src<0) ? (u16)0 : f2bf(W[src*128 + n]);
  }
  int4 o;
  o.x=(int)((u32)v[0]|((u32)v[1]<<16)); o.y=(int)((u32)v[2]|((u32)v[3]<<16));
  o.z=(int)((u32)v[4]|((u32)v[5]<<16)); o.w=(int)((u32)v[6]|((u32)v[7]<<16));
  *(int4*)&wsw[base + rel*8] = o;
}

// ---------------------------------------------------------------- fused ballq + MLP
__device__ __forceinline__ void zero_C(f4v C[2][8]){
  #pragma unroll
  for(int mt=0;mt<2;mt++)
    #pragma unroll
    for(int t=0;t<8;t++) C[mt][t] = (f4v){0.f,0.f,0.f,0.f};
}
__device__ __forceinline__ void load_bias(const float* bsrc,int l15,float bb[8]){
  #pragma unroll
  for(int t=0;t<8;t++) bb[t]=bsrc[t*16+l15];
}
template<int KC>
__device__ __forceinline__ void run_gemm(const u16* A, const u16* BW,
                                         int lane,int l15,int quad, f4v C[2][8]){
  s8v af[2][KC];
  #pragma unroll
  for(int mt=0;mt<2;mt++)
    #pragma unroll
    for(int c=0;c<KC;c++)
      af[mt][c] = *(const s8v*)&A[(mt*16+l15)*STRIDE + c*32 + quad*8];
  #pragma unroll
  for(int t=0;t<8;t++){
    #pragma unroll
    for(int c=0;c<KC;c++){
      s8v bw = *(const s8v*)&BW[((c*8+t)*64 + lane)*8];
      C[0][t] = __builtin_amdgcn_mfma_f32_16x16x32_bf16(af[0][c],bw,C[0][t],0,0,0);
      C[1][t] = __builtin_amdgcn_mfma_f32_16x16x32_bf16(af[1][c],bw,C[1][t],0,0,0);
    }
  }
}
__device__ __forceinline__ void store_act(u16* A,int l15,int quad,f4v C[2][8],const float bb[8]){
  #pragma unroll
  for(int mt=0;mt<2;mt++)
    #pragma unroll
    for(int t=0;t<8;t++)
      #pragma unroll
      for(int r=0;r<4;r++){
        float v = fmaxf(C[mt][t][r]+bb[t], 0.f);
        A[(mt*16+quad*4+r)*STRIDE + t*16 + l15] = f2bf(v);
      }
}
__device__ __forceinline__ void write_xyz_chunk0(u16* A,int lane,float xn,float yn,float zn){
  if(lane<32){
    u16* row=&A[lane*STRIDE];
    row[0]=f2bf(xn); row[1]=f2bf(yn); row[2]=f2bf(zn); row[3]=0;
    #pragma unroll
    for(int q=0;q<7;q++) *(u64*)&row[4+q*4] = 0ull;   // cols 4..31 zero
  }
}

__global__ __launch_bounds__(256,3) void mlp_kernel(const float* __restrict__ xyz,
    const float* __restrict__ feats, const u16* __restrict__ wsw,
    const float* __restrict__ b1,const float* __restrict__ b2,const float* __restrict__ b3,const float* __restrict__ b4,
    const float* __restrict__ newxyz, float* __restrict__ fout){
  __shared__ __align__(16) u16 Abuf[4][32*STRIDE];
  __shared__ u64 Bcand[4][CAP];
  __shared__ int selbuf[4][32];
  const int tid=threadIdx.x, wv=tid>>6, lane=tid&63, quad=lane>>4, l15=lane&15;
  const int widx = blockIdx.x*4 + wv, b = widx>>10;
  u16* A = Abuf[wv];
  const float* xb = xyz + (size_t)b*4096*3;
  // exact f32 FPS center
  const float cx=newxyz[widx*3], cy=newxyz[widx*3+1], cz=newxyz[widx*3+2];

  // ---- ball query (per wave; dedicated LDS candidate buffer) ----
  {
    u64* Bc = Bcand[wv];
    int* sel = selbuf[wv];
    const u64 lt = (1ull<<lane)-1ull;
    int base=0;
    for(int kk=0;kk<64;kk++){
      int p = kk*64 + lane;
      float d = sqd(cx,cy,cz, xb[p*3],xb[p*3+1],xb[p*3+2]);
      bool in = (d <= 0.04f);
      u64 m = __ballot(in);
      if(in){ int pos = base + __popcll(m&lt); if(pos<CAP) Bc[pos] = ((u64)__float_as_uint(d)<<32)|(u32)p; }
      base += __popcll(m);
    }
    int cnt = base>CAP ? CAP : base;
    if(cnt > 32){
      for(int c=lane; c<cnt; c+=64){
        u64 key = Bc[c]; int r=0;
        for(int t2=0;t2<cnt;t2++) r += (Bc[t2] < key) ? 1 : 0;
        if(r < 32) sel[r] = (int)(u32)key;   // low 32 = point index
      }
    } else {
      for(int c=lane; c<cnt; c+=64) sel[c] = (int)(u32)Bc[c];
      int need = 32 - cnt, b2 = 0;
      for(int kk=0; kk<64 && b2<need; kk++){
        int p = kk*64 + lane;
        float d = sqd(cx,cy,cz, xb[p*3],xb[p*3+1],xb[p*3+2]);
        bool o = !(d <= 0.04f);
        u64 m = __ballot(o);
        if(o){ int pos = b2 + __popcll(m&lt); if(pos<need) sel[cnt+pos] = p; }
        b2 += __popcll(m);
      }
    }
  }
  const int* sel = selbuf[wv];             // same wave wrote it
  const int gi_f = sel[lane>>1] & 4095;
  const int gi_x = sel[lane & 31] & 4095;

  // ---- stage grouped features (f32 -> bf16) -> cols 32..95 ----
  {
    int r2=lane>>1, h=lane&1;
    const float* fs = feats + ((size_t)b*4096 + gi_f)*64 + h*32;
    u16* fd = &A[r2*STRIDE + 32 + h*32];
    #pragma unroll
    for(int j=0;j<8;j++){
      float4 v4 = ((const float4*)fs)[j];
      u64 pk4 = (u64)f2bf(v4.x) | ((u64)f2bf(v4.y)<<16)
              | ((u64)f2bf(v4.z)<<32) | ((u64)f2bf(v4.w)<<48);
      *(u64*)&fd[j*4] = pk4;
    }
  }
  // ---- grouped_xyz_norm -> chunk0 cols 0..2 (+ zero pad 3..31) ----
  float xn=0.f,yn=0.f,zn=0.f;
  if(lane<32){
    const float* xp = xb + (size_t)gi_x*3;
    xn = xp[0]-cx; yn = xp[1]-cy; zn = xp[2]-cz;
  }
  write_xyz_chunk0(A,lane,xn,yn,zn);
  __syncthreads();

  f4v C[2][8]; float bb[8];
  // GEMM1: f_in(32x96) @ W1 -> relu -> H1
  zero_C(C); load_bias(b1,l15,bb);
  run_gemm<3>(A, wsw+OFF_G1, lane,l15,quad, C);
  store_act(A,l15,quad,C,bb);
  __syncthreads();
  // GEMM2: H1 @ W2 -> relu -> f_prime
  zero_C(C); load_bias(b2,l15,bb);
  run_gemm<4>(A, wsw+OFF_G2, lane,l15,quad, C);
  float fp[2][8][4]; float mean[8];
  #pragma unroll
  for(int t=0;t<8;t++){
    float s=0.f;
    #pragma unroll
    for(int mt=0;mt<2;mt++)
      #pragma unroll
      for(int r=0;r<4;r++){
        float v = fmaxf(C[mt][t][r]+bb[t], 0.f);
        fp[mt][t][r]=v; s+=v;
      }
    s += __shfl_xor(s,16); s += __shfl_xor(s,32);
    mean[t] = s*0.03125f;
  }
  #pragma unroll
  for(int mt=0;mt<2;mt++)
    #pragma unroll
    for(int t=0;t<8;t++)
      #pragma unroll
      for(int r=0;r<4;r++)
        A[(mt*16+quad*4+r)*STRIDE + 32 + t*16 + l15] = f2bf(fp[mt][t][r]-mean[t]);
  write_xyz_chunk0(A,lane,xn,yn,zn);   // w_in chunk0
  __syncthreads();
  // GEMM3: w_in(32x160) @ W3 -> relu -> H3
  zero_C(C); load_bias(b3,l15,bb);
  run_gemm<5>(A, wsw+OFF_G3, lane,l15,quad, C);
  store_act(A,l15,quad,C,bb);
  __syncthreads();
  // GEMM4: H3 @ W4 -> sigmoid -> alpha; f_out = sum_k alpha*f_prime
  zero_C(C); load_bias(b4,l15,bb);
  run_gemm<4>(A, wsw+OFF_G4, lane,l15,quad, C);
  float* fo = fout + (size_t)widx*128;
  #pragma unroll
  for(int t=0;t<8;t++){
    float part=0.f;
    #pragma unroll
    for(int mt=0;mt<2;mt++)
      #pragma unroll
      for(int r=0;r<4;r++){
        float pre = C[mt][t][r]+bb[t];
        float a = 1.f/(1.f+__expf(-pre));
        part += a*fp[mt][t][r];
      }
    part += __shfl_xor(part,16); part += __shfl_xor(part,32);
    if(quad==0) fo[t*16+l15] = part;
  }
}

// ---------------------------------------------------------------- launch
extern "C" void kernel_launch(void* const* d_in, const int* in_sizes, int n_in,
                              void* d_out, int out_size, void* d_ws, size_t ws_size,
                              hipStream_t stream){
  (void)in_sizes; (void)n_in; (void)out_size; (void)ws_size;
  const float* xyz   = (const float*)d_in[0];
  const float* feats = (const float*)d_in[1];
  const float* W1 = (const float*)d_in[2]; const float* b1 = (const float*)d_in[3];
  const float* W2 = (const float*)d_in[4]; const float* b2 = (const float*)d_in[5];
  const float* W3 = (const float*)d_in[6]; const float* b3 = (const float*)d_in[7];
  const float* W4 = (const float*)d_in[8]; const float* b4 = (const float*)d_in[9];
  float* out = (float*)d_out;
  float* newxyz = out;               // (16,1024,3) f32
  float* fout   = out + 16*1024*3;   // (16,1024,128) f32
  u16* wsw = (u16*)d_ws;             // 128 KiB swizzled bf16 weights — only ws use

  hipLaunchKernelGGL(swz_kernel, dim3(32),   dim3(256), 0, stream, W1,W2,W3,W4, wsw);
  hipLaunchKernelGGL(fps_kernel, dim3(16),   dim3(256), 0, stream, xyz, newxyz);
  hipLaunchKernelGGL(mlp_kernel, dim3(4096), dim3(256), 0, stream,
                     xyz, feats, wsw, b1,b2,b3,b4, newxyz, fout);
}